// Round 6
// baseline (603.682 us; speedup 1.0000x reference)
//
#include <hip/hip_runtime.h>

// GNNML3 forward. R6: (a) deg counters padded to one per 64B sector (memory-side
// atomic RMW serializes per sector; 16 counters/sector was 512-deep queues);
// (b) aggregate+transform fused into k_layer: aggregation writes the LDS A-tile
// directly, then MFMA GEMM in the same block -> saves 64MB/layer global traffic.

#define Nn   50000
#define Ne   1600000
#define Gg   128
#define NEk  5
#define NINf 16
#define NCLSo 6
#define NB   196        // ceil((Nn+1)/256)
#define SPAD 41         // uint4 row stride of LDS A-tile (656B = 640 + 16 pad)

using short8 = __attribute__((ext_vector_type(8))) short;
using f32x4  = __attribute__((ext_vector_type(4))) float;

__device__ __forceinline__ float2 bf2u(unsigned u) {
    return make_float2(__uint_as_float(u << 16), __uint_as_float(u & 0xffff0000u));
}
__device__ __forceinline__ unsigned f2bf(float a, float b) {
    unsigned ua = __float_as_uint(a), ub = __float_as_uint(b);
    ua += 0x7fffu + ((ua >> 16) & 1u);
    ub += 0x7fffu + ((ub >> 16) & 1u);
    return (ua >> 16) | (ub & 0xffff0000u);
}
__device__ __forceinline__ unsigned short f2bf1(float a) {
    unsigned ua = __float_as_uint(a);
    ua += 0x7fffu + ((ua >> 16) & 1u);
    return (unsigned short)(ua >> 16);
}

// ---------------- prep kernels ----------------

__global__ void k_pad_x(const float* __restrict__ x, unsigned* __restrict__ h0) {
    int i = blockIdx.x * 256 + threadIdx.x;           // over Nn*32
    if (i >= Nn * 32) return;
    int n = i >> 5, p = i & 31;
    int f0 = 2 * p;
    float v0 = (f0 < NINf) ? x[n * NINf + f0] : 0.f;
    float v1 = (f0 + 1 < NINf) ? x[n * NINf + f0 + 1] : 0.f;
    h0[i] = f2bf(v0, v1);
}

__global__ void k_pad_w1(const float* __restrict__ W1, float* __restrict__ W1p) {
    int i = blockIdx.x * 256 + threadIdx.x;           // over 5*64*64
    if (i >= NEk * 64 * 64) return;
    int h = i & 63, f = (i >> 6) & 63, k = i >> 12;
    W1p[i] = (f < NINf) ? W1[(k * NINf + f) * 64 + h] : 0.f;
}

// pack W[320][64] fp32 into MFMA B-fragment layout, split hi/lo bf16.
// index: ((nt*10 + kstep)*64 + lane)*8 + j ; k = kstep*32 + (lane>>4)*8 + j,
// col = nt*16 + (lane&15).
__global__ void k_pack_b(const float* __restrict__ W, unsigned short* __restrict__ bhi,
                         unsigned short* __restrict__ blo) {
    int i = blockIdx.x * 256 + threadIdx.x;
    if (i >= 20480) return;
    int j = i & 7, lane = (i >> 3) & 63, t2 = i >> 9;   // t2 = nt*10+kstep
    int nt = t2 / 10, kstep = t2 - nt * 10;
    int k = kstep * 32 + (lane >> 4) * 8 + j;
    int col = nt * 16 + (lane & 15);
    float v = W[k * 64 + col];
    unsigned short hi = f2bf1(v);
    float fhi = __uint_as_float(((unsigned)hi) << 16);
    bhi[i] = hi;
    blo[i] = f2bf1(v - fhi);
}

// rank[e] = arrival index within dst bucket; deg padded: counter n at deg[n*16]
__global__ void k_rank(const int* __restrict__ ei, int* __restrict__ deg,
                       int* __restrict__ rank) {
    int e = blockIdx.x * 256 + threadIdx.x;
    if (e >= Ne) return;
    rank[e] = atomicAdd(&deg[ei[Ne + e] * 16], 1);
}

// -------- 3-phase exclusive scan of padded deg -> rowstart --------

__global__ void k_blocksum(const int* __restrict__ deg, int* __restrict__ bsum) {
    __shared__ int l[256];
    int t = threadIdx.x;
    int i = blockIdx.x * 256 + t;
    l[t] = (i < Nn) ? deg[i * 16] : 0;
    __syncthreads();
    for (int off = 128; off > 0; off >>= 1) {
        if (t < off) l[t] += l[t + off];
        __syncthreads();
    }
    if (t == 0) bsum[blockIdx.x] = l[0];
}

__global__ void k_scanpart(const int* __restrict__ bsum, int* __restrict__ boff) {
    __shared__ int l[256];
    int t = threadIdx.x;
    int v = (t < NB) ? bsum[t] : 0;
    l[t] = v;
    __syncthreads();
    for (int off = 1; off < 256; off <<= 1) {
        int u = (t >= off) ? l[t - off] : 0;
        __syncthreads();
        l[t] += u;
        __syncthreads();
    }
    if (t < NB) boff[t] = l[t] - v;                   // exclusive
}

__global__ void k_scanfinal(const int* __restrict__ deg, const int* __restrict__ boff,
                            int* __restrict__ rowstart) {
    __shared__ int l[256];
    int t = threadIdx.x;
    int i = blockIdx.x * 256 + t;
    int v = (i < Nn) ? deg[i * 16] : 0;
    l[t] = v;
    __syncthreads();
    for (int off = 1; off < 256; off <<= 1) {
        int u = (t >= off) ? l[t - off] : 0;
        __syncthreads();
        l[t] += u;
        __syncthreads();
    }
    if (i <= Nn) rowstart[i] = boff[blockIdx.x] + l[t] - v;
}

// deterministic placement: 16B record {src, bf16 a0..a4} to pos
__global__ void k_place(const int* __restrict__ ei, const float* __restrict__ eattr,
                        const int* __restrict__ rowstart, const int* __restrict__ rank,
                        uint4* __restrict__ recs) {
    int e = blockIdx.x * 256 + threadIdx.x;
    if (e >= Ne) return;
    int d = ei[Ne + e];
    int pos = rowstart[d] + rank[e];
    const float* a = eattr + (size_t)e * 5;
    uint4 r;
    r.x = (unsigned)ei[e];
    r.y = f2bf(a[0], a[1]);
    r.z = f2bf(a[2], a[3]);
    r.w = f2bf(a[4], 0.f);
    recs[pos] = r;
}

// batch is sorted -> segment bounds by boundary detection
__global__ void k_bounds(const int* __restrict__ batch, int* __restrict__ sg,
                         int* __restrict__ eg) {
    int n = blockIdx.x * 256 + threadIdx.x;
    if (n >= Nn) return;
    int g = batch[n];
    if (n == 0) sg[g] = 0;
    else {
        int gp = batch[n - 1];
        if (gp != g) { sg[g] = n; eg[gp] = n; }
    }
    if (n == Nn - 1) eg[g] = Nn;
}

// ---------------- fused layer kernel ----------------
// 512 threads = 8 waves, 64 nodes per block.
// Phase 1: wave w aggregates nodes w*8..w*8+7 into the LDS A-tile (bf16, SPAD rows).
// Phase 2: MFMA GEMM A[64x320] x (Whi+Wlo)[320x64]: wave -> mtile=w&3, ntile pair w>>2.
// Phase 3: C spill to LDS fp32, bias+relu, pack bf16, coalesced store.
__global__ __launch_bounds__(512) void k_layer(
    const unsigned* __restrict__ hin, const int* __restrict__ rowstart,
    const uint4* __restrict__ recs, const unsigned short* __restrict__ bhi,
    const unsigned short* __restrict__ blo, const float* __restrict__ bias,
    unsigned* __restrict__ outh) {
    __shared__ uint4 smem[64 * SPAD];                  // 41984 B
    int t = threadIdx.x;
    int lane = t & 63, wave = t >> 6;
    int l = lane & 31, half = lane >> 5;
    unsigned* As = (unsigned*)smem;

    // ---- phase 1: aggregation into LDS ----
    for (int i = 0; i < 8; ++i) {
        int row = wave * 8 + i;
        int node = __builtin_amdgcn_readfirstlane(blockIdx.x * 64 + row);
        float2 c0 = {0.f, 0.f}, c1 = c0, c2 = c0, c3 = c0, c4 = c0;
        if (node < Nn) {
            int beg = rowstart[node], end = rowstart[node + 1];
            int ee = beg;
#define EDGE(E) { \
    uint4 r = recs[(E)]; \
    unsigned hx = hin[(size_t)(int)r.x * 32 + l]; \
    float2 xv = bf2u(hx); \
    float2 A01 = bf2u(r.y), A23 = bf2u(r.z); \
    float a4v = __uint_as_float(r.w << 16); \
    c0.x = fmaf(A01.x, xv.x, c0.x); c0.y = fmaf(A01.x, xv.y, c0.y); \
    c1.x = fmaf(A01.y, xv.x, c1.x); c1.y = fmaf(A01.y, xv.y, c1.y); \
    c2.x = fmaf(A23.x, xv.x, c2.x); c2.y = fmaf(A23.x, xv.y, c2.y); \
    c3.x = fmaf(A23.y, xv.x, c3.x); c3.y = fmaf(A23.y, xv.y, c3.y); \
    c4.x = fmaf(a4v,  xv.x, c4.x); c4.y = fmaf(a4v,  xv.y, c4.y); }
            for (; ee + 8 <= end; ee += 8) {
                EDGE(ee + half) EDGE(ee + 2 + half) EDGE(ee + 4 + half) EDGE(ee + 6 + half)
            }
            for (; ee + 2 <= end; ee += 2) { EDGE(ee + half) }
            if (ee < end) { if (half == 0) { EDGE(ee) } }
#undef EDGE
            // fold half 1 into half 0
            c0.x += __shfl(c0.x, lane ^ 32); c0.y += __shfl(c0.y, lane ^ 32);
            c1.x += __shfl(c1.x, lane ^ 32); c1.y += __shfl(c1.y, lane ^ 32);
            c2.x += __shfl(c2.x, lane ^ 32); c2.y += __shfl(c2.y, lane ^ 32);
            c3.x += __shfl(c3.x, lane ^ 32); c3.y += __shfl(c3.y, lane ^ 32);
            c4.x += __shfl(c4.x, lane ^ 32); c4.y += __shfl(c4.y, lane ^ 32);
        }
        if (half == 0) {
            unsigned* o = As + row * (SPAD * 4) + l;
            o[0]   = f2bf(c0.x, c0.y);
            o[32]  = f2bf(c1.x, c1.y);
            o[64]  = f2bf(c2.x, c2.y);
            o[96]  = f2bf(c3.x, c3.y);
            o[128] = f2bf(c4.x, c4.y);
        }
    }
    __syncthreads();

    // ---- phase 2: MFMA GEMM ----
    int m = lane & 15, quad = lane >> 4;
    int mtile = wave & 3, np = wave >> 2;              // np: ntile pair {2np, 2np+1}
    f32x4 acc0 = {0.f, 0.f, 0.f, 0.f}, acc1 = acc0;
    const uint4* arow = smem + (mtile * 16 + m) * SPAD + quad;
#pragma unroll 2
    for (int ks = 0; ks < 10; ++ks) {
        short8 a = *(const short8*)(arow + ks * 4);
        size_t b0 = ((size_t)((2 * np) * 10 + ks) * 64 + lane) * 8;
        size_t b1 = ((size_t)((2 * np + 1) * 10 + ks) * 64 + lane) * 8;
        short8 h0 = *(const short8*)(bhi + b0);
        short8 l0 = *(const short8*)(blo + b0);
        acc0 = __builtin_amdgcn_mfma_f32_16x16x32_bf16(a, h0, acc0, 0, 0, 0);
        acc0 = __builtin_amdgcn_mfma_f32_16x16x32_bf16(a, l0, acc0, 0, 0, 0);
        short8 h1 = *(const short8*)(bhi + b1);
        short8 l1 = *(const short8*)(blo + b1);
        acc1 = __builtin_amdgcn_mfma_f32_16x16x32_bf16(a, h1, acc1, 0, 0, 0);
        acc1 = __builtin_amdgcn_mfma_f32_16x16x32_bf16(a, l1, acc1, 0, 0, 0);
    }
    __syncthreads();                                   // A-tile reads done

    // ---- phase 3: epilogue via LDS ----
    float* Cs = (float*)smem;                          // [64 rows][66] fp32
#pragma unroll
    for (int r = 0; r < 4; ++r) {
        int row = mtile * 16 + quad * 4 + r;
        Cs[row * 66 + (2 * np) * 16 + m]     = acc0[r];
        Cs[row * 66 + (2 * np + 1) * 16 + m] = acc1[r];
    }
    __syncthreads();

    int row = t >> 3, cg = t & 7;                      // 8 threads/row, 8 cols each
    int node = blockIdx.x * 64 + row;
    if (node < Nn) {
        const float* cr = Cs + row * 66 + cg * 8;
        const float* bb = bias + cg * 8;
        unsigned o[4];
#pragma unroll
        for (int j = 0; j < 4; ++j) {
            float v0 = fmaxf(cr[2 * j]     + bb[2 * j],     0.f);
            float v1 = fmaxf(cr[2 * j + 1] + bb[2 * j + 1], 0.f);
            o[j] = f2bf(v0, v1);
        }
        *(uint4*)(outh + (size_t)node * 32 + cg * 4) = make_uint4(o[0], o[1], o[2], o[3]);
    }
}

// ---------------- pooling + head ----------------

__global__ __launch_bounds__(256) void k_pool(const unsigned* __restrict__ h,
                                              const int* __restrict__ sg,
                                              const int* __restrict__ eg,
                                              float* __restrict__ pooled) {
    __shared__ float2 ls[256], lm[256];
    int g = blockIdx.x, t = threadIdx.x;
    int p = t & 31, q = t >> 5;                        // 32 feature-pairs x 8 node-strides
    int s = sg[g], e = eg[g];
    float2 sum = {0.f, 0.f}, mx = {0.f, 0.f};          // relu>=0 -> 0 valid max identity
    for (int n = s + q; n < e; n += 8) {
        float2 v = bf2u(h[(size_t)n * 32 + p]);
        sum.x += v.x; sum.y += v.y;
        mx.x = fmaxf(mx.x, v.x); mx.y = fmaxf(mx.y, v.y);
    }
    ls[t] = sum; lm[t] = mx;
    __syncthreads();
    if (t < 32) {
        float2 ss = ls[t], mm = lm[t];
        for (int i = 1; i < 8; ++i) {
            float2 a = ls[t + i * 32], b = lm[t + i * 32];
            ss.x += a.x; ss.y += a.y;
            mm.x = fmaxf(mm.x, b.x); mm.y = fmaxf(mm.y, b.y);
        }
        pooled[g * 128 + 2 * t]          = ss.x;
        pooled[g * 128 + 2 * t + 1]      = ss.y;
        pooled[g * 128 + 64 + 2 * t]     = mm.x;
        pooled[g * 128 + 64 + 2 * t + 1] = mm.y;
    }
}

__global__ void k_head(const float* __restrict__ pooled, const float* __restrict__ gamma,
                       const float* __restrict__ beta, const float* __restrict__ mean,
                       const float* __restrict__ var, const float* __restrict__ fcw,
                       const float* __restrict__ fcb, float* __restrict__ out) {
    __shared__ float y[128];
    __shared__ float lg[8];
    int g = blockIdx.x, c = threadIdx.x;   // 128 threads
    float p = pooled[g * 128 + c];
    y[c] = (p - mean[c]) * rsqrtf(var[c] + 1e-5f) * gamma[c] + beta[c];
    __syncthreads();
    if (c < NCLSo) {
        float l = fcb[c];
        for (int i = 0; i < 128; ++i) l += y[i] * fcw[i * NCLSo + c];
        lg[c] = l;
    }
    __syncthreads();
    if (c == 0) {
        float m = lg[0];
        for (int j = 1; j < NCLSo; ++j) m = fmaxf(m, lg[j]);
        float se = 0.f;
        for (int j = 0; j < NCLSo; ++j) se += expf(lg[j] - m);
        float lse = m + logf(se);
        for (int j = 0; j < NCLSo; ++j) out[g * NCLSo + j] = lg[j] - lse;
    }
}

// ---------------- launch ----------------

static inline size_t rup(size_t x) { return (x + 255) & ~(size_t)255; }

extern "C" void kernel_launch(void* const* d_in, const int* in_sizes, int n_in,
                              void* d_out, int out_size, void* d_ws, size_t ws_size,
                              hipStream_t stream) {
    const float* x     = (const float*)d_in[0];
    const int*   ei    = (const int*)d_in[1];
    const float* eattr = (const float*)d_in[2];
    const int*   batch = (const int*)d_in[3];
    const float* W1    = (const float*)d_in[4];
    const float* b1    = (const float*)d_in[5];
    const float* W2    = (const float*)d_in[6];
    const float* b2    = (const float*)d_in[7];
    const float* W3    = (const float*)d_in[8];
    const float* b3    = (const float*)d_in[9];
    const float* W4    = (const float*)d_in[10];
    const float* b4    = (const float*)d_in[11];
    const float* gamma = (const float*)d_in[12];
    const float* beta  = (const float*)d_in[13];
    const float* mean  = (const float*)d_in[14];
    const float* var   = (const float*)d_in[15];
    const float* fcw   = (const float*)d_in[16];
    const float* fcb   = (const float*)d_in[17];
    float* out = (float*)d_out;

    char* p = (char*)d_ws;
    auto take = [&](size_t bytes) { char* r = p; p += rup(bytes); return r; };
    int*            deg      = (int*)take((size_t)(Nn + 1) * 64);   // padded: 1 counter/64B
    int*            rowstart = (int*)take((size_t)(Nn + 1) * 4);
    int*            bsum     = (int*)take((size_t)NB * 4);
    int*            boff     = (int*)take((size_t)NB * 4);
    int*            rank     = (int*)take((size_t)Ne * 4);
    uint4*          recs     = (uint4*)take((size_t)Ne * 16);
    unsigned*       hA       = (unsigned*)take((size_t)Nn * 32 * 4);
    unsigned*       hB       = (unsigned*)take((size_t)Nn * 32 * 4);
    float*          W1p      = (float*)take((size_t)NEk * 64 * 64 * 4);
    unsigned short* bhiA     = (unsigned short*)take((size_t)4 * 20480 * 2);
    unsigned short* bloA     = (unsigned short*)take((size_t)4 * 20480 * 2);
    float*          pooled   = (float*)take((size_t)Gg * 128 * 4);
    int*            sg       = (int*)take((size_t)Gg * 4);
    int*            eg       = (int*)take((size_t)Gg * 4);

    hipMemsetAsync(deg, 0, (size_t)(Nn + 1) * 64, stream);

    k_pad_x<<<(Nn * 32 + 255) / 256, 256, 0, stream>>>(x, hA);
    k_pad_w1<<<(NEk * 64 * 64 + 255) / 256, 256, 0, stream>>>(W1, W1p);
    k_pack_b<<<80, 256, 0, stream>>>(W1p, bhiA,             bloA);
    k_pack_b<<<80, 256, 0, stream>>>(W2,  bhiA + 20480,     bloA + 20480);
    k_pack_b<<<80, 256, 0, stream>>>(W3,  bhiA + 2 * 20480, bloA + 2 * 20480);
    k_pack_b<<<80, 256, 0, stream>>>(W4,  bhiA + 3 * 20480, bloA + 3 * 20480);
    k_rank<<<(Ne + 255) / 256, 256, 0, stream>>>(ei, deg, rank);
    k_blocksum<<<NB, 256, 0, stream>>>(deg, bsum);
    k_scanpart<<<1, 256, 0, stream>>>(bsum, boff);
    k_scanfinal<<<NB, 256, 0, stream>>>(deg, boff, rowstart);
    k_place<<<(Ne + 255) / 256, 256, 0, stream>>>(ei, eattr, rowstart, rank, recs);
    k_bounds<<<(Nn + 255) / 256, 256, 0, stream>>>(batch, sg, eg);

    const float* bs[4] = { b1, b2, b3, b4 };
    unsigned* cur = hA;
    unsigned* nxt = hB;
    for (int L = 0; L < 4; ++L) {
        k_layer<<<(Nn + 63) / 64, 512, 0, stream>>>(
            cur, rowstart, recs, bhiA + (size_t)L * 20480, bloA + (size_t)L * 20480,
            bs[L], nxt);
        unsigned* tmp = cur; cur = nxt; nxt = tmp;
    }

    k_pool<<<Gg, 256, 0, stream>>>(cur, sg, eg, pooled);
    k_head<<<Gg, 128, 0, stream>>>(pooled, gamma, beta, mean, var, fcw, fcb, out);
}